// Round 1
// baseline (38.778 us; speedup 1.0000x reference)
//
#include <hip/hip_runtime.h>

constexpr int BLOCK = 256;

// Each thread handles 4 consecutive rows (20 floats = 5 float4, 16B-aligned).
__global__ __launch_bounds__(BLOCK) void rhs_kernel(
    const float* __restrict__ x, const float* __restrict__ w,
    float* __restrict__ out, int nthreads)
{
    int t = blockIdx.x * BLOCK + threadIdx.x;
    if (t >= nthreads) return;

    // 10^weights (uniform across threads; w loads become scalar loads)
    float w10[12];
#pragma unroll
    for (int k = 0; k < 12; ++k) w10[k] = exp10f(w[k]);

    const float4* xv = reinterpret_cast<const float4*>(x) + (size_t)t * 5;
    float r[20];
#pragma unroll
    for (int i = 0; i < 5; ++i) {
        float4 v = xv[i];
        r[4*i+0] = v.x; r[4*i+1] = v.y; r[4*i+2] = v.z; r[4*i+3] = v.w;
    }

    float o[20];
#pragma unroll
    for (int i = 0; i < 4; ++i) {
        float z0 = r[5*i+0], z1 = r[5*i+1], z2 = r[5*i+2],
              z3 = r[5*i+3], z4 = r[5*i+4];
        // S columns pair up as (2p, 2p+1) = negatives of each other:
        // g_p = w10[2p]*t[2p] - w10[2p+1]*t[2p+1]
        float g0 = w10[0]  * (z0*z0) - w10[1]  * z1;
        float g1 = w10[2]  * (z0*z3) - w10[3]  * z2;
        float g2 = w10[4]  * (z3*z3) - w10[5]  * z4;
        float g3 = w10[6]  * (z1*z4) - w10[7]  * (z2*z2);
        float g4 = w10[8]  * (z1*z3) - w10[9]  * (z0*z2);
        float g5 = w10[10] * (z0*z4) - w10[11] * (z2*z3);
        // xdot = P @ g with P = S[:, even columns]
        o[5*i+0] = -2.f*g0 - g1      + g4 - g5;
        o[5*i+1] =      g0      - g3 - g4;
        o[5*i+2] =      g1 + 2.f*g3 + g4 + g5;
        o[5*i+3] =     -g1 - 2.f*g2 - g4 + g5;
        o[5*i+4] =      g2      - g3      - g5;
    }

    float4* ov = reinterpret_cast<float4*>(out) + (size_t)t * 5;
#pragma unroll
    for (int i = 0; i < 5; ++i) {
        float4 v;
        v.x = o[4*i+0]; v.y = o[4*i+1]; v.z = o[4*i+2]; v.w = o[4*i+3];
        ov[i] = v;
    }
}

extern "C" void kernel_launch(void* const* d_in, const int* in_sizes, int n_in,
                              void* d_out, int out_size, void* d_ws, size_t ws_size,
                              hipStream_t stream) {
    const float* x = (const float*)d_in[0];
    const float* w = (const float*)d_in[1];
    float* out = (float*)d_out;

    int nrows = in_sizes[0] / 5;          // 4194304
    int nthreads = nrows / 4;             // 4 rows per thread (B divisible by 4)
    int grid = (nthreads + BLOCK - 1) / BLOCK;
    rhs_kernel<<<grid, BLOCK, 0, stream>>>(x, w, out, nthreads);
}

// Round 2
// 31.500 us; speedup vs baseline: 1.2311x; 1.2311x over previous
//
#include <hip/hip_runtime.h>

constexpr int BLOCK = 256;
// Each thread computes 4 rows = 20 floats; block tile = 256*20 floats = 20 KiB.
constexpr int TILE_VEC4 = BLOCK * 5;   // 1280 float4 per block

__global__ __launch_bounds__(BLOCK) void rhs_kernel(
    const float* __restrict__ x, const float* __restrict__ w,
    float* __restrict__ out, int n_vec4)
{
    __shared__ float4 tile[TILE_VEC4];  // 20 KiB

    const int tid = threadIdx.x;
    const size_t base = (size_t)blockIdx.x * TILE_VEC4;
    const float4* xv = reinterpret_cast<const float4*>(x) + base;
    float4*       ov = reinterpret_cast<float4*>(out) + base;

    // 10^weights (wave-uniform -> scalar loads)
    float w10[12];
#pragma unroll
    for (int k = 0; k < 12; ++k) w10[k] = exp10f(w[k]);

    // Coalesced global -> LDS (lane-contiguous float4)
#pragma unroll
    for (int k = 0; k < 5; ++k) {
        int idx = k * BLOCK + tid;
        if (base + idx < (size_t)n_vec4) tile[idx] = xv[idx];
    }
    __syncthreads();

    // Per-thread: read own 5 float4 (stride 80 B -> conflict-free b128 reads)
    float4* my = &tile[tid * 5];
    float r[20];
#pragma unroll
    for (int i = 0; i < 5; ++i) {
        float4 v = my[i];
        r[4*i+0] = v.x; r[4*i+1] = v.y; r[4*i+2] = v.z; r[4*i+3] = v.w;
    }

    float o[20];
#pragma unroll
    for (int i = 0; i < 4; ++i) {
        float z0 = r[5*i+0], z1 = r[5*i+1], z2 = r[5*i+2],
              z3 = r[5*i+3], z4 = r[5*i+4];
        // S columns pair as negatives: g_p = w10[2p]*t[2p] - w10[2p+1]*t[2p+1]
        float g0 = w10[0]  * (z0*z0) - w10[1]  * z1;
        float g1 = w10[2]  * (z0*z3) - w10[3]  * z2;
        float g2 = w10[4]  * (z3*z3) - w10[5]  * z4;
        float g3 = w10[6]  * (z1*z4) - w10[7]  * (z2*z2);
        float g4 = w10[8]  * (z1*z3) - w10[9]  * (z0*z2);
        float g5 = w10[10] * (z0*z4) - w10[11] * (z2*z3);
        o[5*i+0] = -2.f*g0 - g1      + g4 - g5;
        o[5*i+1] =      g0      - g3 - g4;
        o[5*i+2] =      g1 + 2.f*g3 + g4 + g5;
        o[5*i+3] =     -g1 - 2.f*g2 - g4 + g5;
        o[5*i+4] =      g2      - g3      - g5;
    }

    // Write results back in place (each thread owns its 80 B region)
#pragma unroll
    for (int i = 0; i < 5; ++i) {
        float4 v;
        v.x = o[4*i+0]; v.y = o[4*i+1]; v.z = o[4*i+2]; v.w = o[4*i+3];
        my[i] = v;
    }
    __syncthreads();

    // Coalesced LDS -> global
#pragma unroll
    for (int k = 0; k < 5; ++k) {
        int idx = k * BLOCK + tid;
        if (base + idx < (size_t)n_vec4) ov[idx] = tile[idx];
    }
}

extern "C" void kernel_launch(void* const* d_in, const int* in_sizes, int n_in,
                              void* d_out, int out_size, void* d_ws, size_t ws_size,
                              hipStream_t stream) {
    const float* x = (const float*)d_in[0];
    const float* w = (const float*)d_in[1];
    float* out = (float*)d_out;

    int n_vec4 = in_sizes[0] / 4;                       // 5,242,880 float4s
    int grid = (n_vec4 + TILE_VEC4 - 1) / TILE_VEC4;    // 4096 blocks
    rhs_kernel<<<grid, BLOCK, 0, stream>>>(x, w, out, n_vec4);
}

// Round 4
// 30.330 us; speedup vs baseline: 1.2785x; 1.0386x over previous
//
#include <hip/hip_runtime.h>

typedef float f32x4 __attribute__((ext_vector_type(4)));

constexpr int BLOCK = 256;
// Each thread computes 4 rows = 20 floats; block tile = 256*20 floats = 20 KiB.
constexpr int TILE_VEC4 = BLOCK * 5;   // 1280 float4 per block

__global__ __launch_bounds__(BLOCK) void rhs_kernel(
    const float* __restrict__ x, const float* __restrict__ w,
    float* __restrict__ out, int n_vec4)
{
    __shared__ f32x4 tile[TILE_VEC4];  // 20 KiB

    const int tid = threadIdx.x;
    const size_t base = (size_t)blockIdx.x * TILE_VEC4;
    const f32x4* xv = reinterpret_cast<const f32x4*>(x) + base;
    f32x4*       ov = reinterpret_cast<f32x4*>(out) + base;

    const bool full = (base + TILE_VEC4) <= (size_t)n_vec4;

    // 10^weights (wave-uniform -> scalar loads)
    float w10[12];
#pragma unroll
    for (int k = 0; k < 12; ++k) w10[k] = exp10f(w[k]);

    // Coalesced global -> LDS (lane-contiguous 16B)
    if (full) {
#pragma unroll
        for (int k = 0; k < 5; ++k) {
            int idx = k * BLOCK + tid;
            tile[idx] = xv[idx];
        }
    } else {
#pragma unroll
        for (int k = 0; k < 5; ++k) {
            int idx = k * BLOCK + tid;
            if (base + idx < (size_t)n_vec4) tile[idx] = xv[idx];
        }
    }
    __syncthreads();

    // Per-thread: read own 5 x 16B (stride 80 B)
    f32x4* my = &tile[tid * 5];
    float r[20];
#pragma unroll
    for (int i = 0; i < 5; ++i) {
        f32x4 v = my[i];
        r[4*i+0] = v.x; r[4*i+1] = v.y; r[4*i+2] = v.z; r[4*i+3] = v.w;
    }

    float o[20];
#pragma unroll
    for (int i = 0; i < 4; ++i) {
        float z0 = r[5*i+0], z1 = r[5*i+1], z2 = r[5*i+2],
              z3 = r[5*i+3], z4 = r[5*i+4];
        // S columns pair as negatives: g_p = w10[2p]*t[2p] - w10[2p+1]*t[2p+1]
        float g0 = w10[0]  * (z0*z0) - w10[1]  * z1;
        float g1 = w10[2]  * (z0*z3) - w10[3]  * z2;
        float g2 = w10[4]  * (z3*z3) - w10[5]  * z4;
        float g3 = w10[6]  * (z1*z4) - w10[7]  * (z2*z2);
        float g4 = w10[8]  * (z1*z3) - w10[9]  * (z0*z2);
        float g5 = w10[10] * (z0*z4) - w10[11] * (z2*z3);
        o[5*i+0] = -2.f*g0 - g1      + g4 - g5;
        o[5*i+1] =      g0      - g3 - g4;
        o[5*i+2] =      g1 + 2.f*g3 + g4 + g5;
        o[5*i+3] =     -g1 - 2.f*g2 - g4 + g5;
        o[5*i+4] =      g2      - g3      - g5;
    }

    // Write results back in place (each thread owns its 80 B region)
#pragma unroll
    for (int i = 0; i < 5; ++i) {
        f32x4 v;
        v.x = o[4*i+0]; v.y = o[4*i+1]; v.z = o[4*i+2]; v.w = o[4*i+3];
        my[i] = v;
    }
    __syncthreads();

    // Coalesced LDS -> global, non-temporal (output never re-read here;
    // keeps L3 free for the input between graph replays)
    if (full) {
#pragma unroll
        for (int k = 0; k < 5; ++k) {
            int idx = k * BLOCK + tid;
            __builtin_nontemporal_store(tile[idx], &ov[idx]);
        }
    } else {
#pragma unroll
        for (int k = 0; k < 5; ++k) {
            int idx = k * BLOCK + tid;
            if (base + idx < (size_t)n_vec4)
                __builtin_nontemporal_store(tile[idx], &ov[idx]);
        }
    }
}

extern "C" void kernel_launch(void* const* d_in, const int* in_sizes, int n_in,
                              void* d_out, int out_size, void* d_ws, size_t ws_size,
                              hipStream_t stream) {
    const float* x = (const float*)d_in[0];
    const float* w = (const float*)d_in[1];
    float* out = (float*)d_out;

    int n_vec4 = in_sizes[0] / 4;                       // 5,242,880 float4s
    int grid = (n_vec4 + TILE_VEC4 - 1) / TILE_VEC4;    // 4096 blocks
    rhs_kernel<<<grid, BLOCK, 0, stream>>>(x, w, out, n_vec4);
}

// Round 5
// 30.105 us; speedup vs baseline: 1.2881x; 1.0075x over previous
//
#include <hip/hip_runtime.h>
#include <stdint.h>

typedef float f32x4 __attribute__((ext_vector_type(4)));

constexpr int BLOCK = 256;
// Each thread computes 4 rows = 20 floats; block tile = 256*20 floats = 20 KiB.
constexpr int TILE_VEC4 = BLOCK * 5;   // 1280 float4 per block

typedef const __attribute__((address_space(1))) void g_void;
typedef __attribute__((address_space(3))) void lds_void;

__global__ __launch_bounds__(BLOCK) void rhs_kernel(
    const float* __restrict__ x, const float* __restrict__ w,
    float* __restrict__ out, int n_vec4)
{
    __shared__ f32x4 tile[TILE_VEC4];  // 20 KiB

    const int tid = threadIdx.x;
    const size_t base = (size_t)blockIdx.x * TILE_VEC4;
    const f32x4* xv = reinterpret_cast<const f32x4*>(x) + base;
    f32x4*       ov = reinterpret_cast<f32x4*>(out) + base;

    const bool full = (base + TILE_VEC4) <= (size_t)n_vec4;

    // 10^weights (wave-uniform -> scalar loads)
    float w10[12];
#pragma unroll
    for (int k = 0; k < 12; ++k) w10[k] = exp10f(w[k]);

    // Coalesced global -> LDS. Full tiles: direct-to-LDS DMA (no VGPR hop).
    // LDS dest is wave-uniform base + lane*16 (the HW-defined layout), which
    // matches tile[k*BLOCK + wave_base + lane] == xv[k*BLOCK + tid].
    if (full) {
        const int wave_base = tid & ~63;
#pragma unroll
        for (int k = 0; k < 5; ++k) {
            int idx = k * BLOCK + tid;
            __builtin_amdgcn_global_load_lds(
                (g_void*)(xv + idx),
                (lds_void*)&tile[k * BLOCK + wave_base],
                16, 0, 0);
        }
    } else {
#pragma unroll
        for (int k = 0; k < 5; ++k) {
            int idx = k * BLOCK + tid;
            if (base + idx < (size_t)n_vec4) tile[idx] = xv[idx];
        }
    }
    __syncthreads();   // compiler drains vmcnt+lgkmcnt before s_barrier

    // Per-thread: read own 5 x 16B (stride 80 B)
    f32x4* my = &tile[tid * 5];
    float r[20];
#pragma unroll
    for (int i = 0; i < 5; ++i) {
        f32x4 v = my[i];
        r[4*i+0] = v.x; r[4*i+1] = v.y; r[4*i+2] = v.z; r[4*i+3] = v.w;
    }

    float o[20];
#pragma unroll
    for (int i = 0; i < 4; ++i) {
        float z0 = r[5*i+0], z1 = r[5*i+1], z2 = r[5*i+2],
              z3 = r[5*i+3], z4 = r[5*i+4];
        // S columns pair as negatives: g_p = w10[2p]*t[2p] - w10[2p+1]*t[2p+1]
        float g0 = w10[0]  * (z0*z0) - w10[1]  * z1;
        float g1 = w10[2]  * (z0*z3) - w10[3]  * z2;
        float g2 = w10[4]  * (z3*z3) - w10[5]  * z4;
        float g3 = w10[6]  * (z1*z4) - w10[7]  * (z2*z2);
        float g4 = w10[8]  * (z1*z3) - w10[9]  * (z0*z2);
        float g5 = w10[10] * (z0*z4) - w10[11] * (z2*z3);
        o[5*i+0] = -2.f*g0 - g1      + g4 - g5;
        o[5*i+1] =      g0      - g3 - g4;
        o[5*i+2] =      g1 + 2.f*g3 + g4 + g5;
        o[5*i+3] =     -g1 - 2.f*g2 - g4 + g5;
        o[5*i+4] =      g2      - g3      - g5;
    }

    // Write results back in place (each thread owns its 80 B region)
#pragma unroll
    for (int i = 0; i < 5; ++i) {
        f32x4 v;
        v.x = o[4*i+0]; v.y = o[4*i+1]; v.z = o[4*i+2]; v.w = o[4*i+3];
        my[i] = v;
    }
    __syncthreads();

    // Coalesced LDS -> global, non-temporal (output never re-read here;
    // keeps L3 free for the input between graph replays)
    if (full) {
#pragma unroll
        for (int k = 0; k < 5; ++k) {
            int idx = k * BLOCK + tid;
            __builtin_nontemporal_store(tile[idx], &ov[idx]);
        }
    } else {
#pragma unroll
        for (int k = 0; k < 5; ++k) {
            int idx = k * BLOCK + tid;
            if (base + idx < (size_t)n_vec4)
                __builtin_nontemporal_store(tile[idx], &ov[idx]);
        }
    }
}

extern "C" void kernel_launch(void* const* d_in, const int* in_sizes, int n_in,
                              void* d_out, int out_size, void* d_ws, size_t ws_size,
                              hipStream_t stream) {
    const float* x = (const float*)d_in[0];
    const float* w = (const float*)d_in[1];
    float* out = (float*)d_out;

    int n_vec4 = in_sizes[0] / 4;                       // 5,242,880 float4s
    int grid = (n_vec4 + TILE_VEC4 - 1) / TILE_VEC4;    // 4096 blocks
    rhs_kernel<<<grid, BLOCK, 0, stream>>>(x, w, out, n_vec4);
}